// Round 2
// baseline (558.541 us; speedup 1.0000x reference)
//
#include <hip/hip_runtime.h>
#include <stdint.h>

#define Bn 2
#define Hn 4
#define Tn 2048
#define Nn 2048
#define Dn 256
#define BH (Bn * Hn)
#define NT 16        // 128-row t-tiles per head
#define NP 136       // triangular tile pairs per head: NT*(NT+1)/2
#define NK 32        // K-steps of 64 over N=2048

typedef __attribute__((ext_vector_type(8))) short short8;
typedef __attribute__((ext_vector_type(4))) float f32x4;

__device__ __forceinline__ uint16_t f2bf(float x) {
  uint32_t u = __float_as_uint(x);
  return (uint16_t)((u + 0x7FFFu + ((u >> 16) & 1u)) >> 16);   // RNE, no NaNs in data
}

__device__ __forceinline__ void gload_lds16(const void* g, void* l) {
  __builtin_amdgcn_global_load_lds((const __attribute__((address_space(1))) uint32_t*)g,
                                   (__attribute__((address_space(3))) uint32_t*)l,
                                   16, 0, 0);
}

// ---------------- RoPE + bf16 cast: QR[bh][t][n] ----------------
__global__ void rope_kernel(const float* __restrict__ Q, uint16_t* __restrict__ QR) {
  size_t v = (size_t)blockIdx.x * blockDim.x + threadIdx.x;  // one thread per 4 elems (2 pairs)
  size_t e = v * 4;
  int n = (int)(e & (Nn - 1));
  int t = (int)((e >> 11) & (Tn - 1));
  const float4 q = *(const float4*)(Q + e);
  int p0 = n >> 1;
  float f0 = exp2f(-(float)p0 * (1.0f / 64.0f)) * 0.15915494309189535f;
  float f1 = exp2f(-(float)(p0 + 1) * (1.0f / 64.0f)) * 0.15915494309189535f;
  float x0 = (float)t * f0, x1 = (float)t * f1;
  float r0 = x0 - floorf(x0), r1 = x1 - floorf(x1);          // revolutions in [0,1)
  float s0 = __builtin_amdgcn_sinf(r0), c0 = __builtin_amdgcn_cosf(r0);  // sin/cos(2*pi*x)
  float s1 = __builtin_amdgcn_sinf(r1), c1 = __builtin_amdgcn_cosf(r1);
  float o0 = q.x * c0 - q.y * s0;
  float o1 = q.y * c0 + q.x * s0;
  float o2 = q.z * c1 - q.w * s1;
  float o3 = q.w * c1 + q.z * s1;
  uint32_t lo = (uint32_t)f2bf(o0) | ((uint32_t)f2bf(o1) << 16);
  uint32_t hi = (uint32_t)f2bf(o2) | ((uint32_t)f2bf(o3) << 16);
  *(uint2*)(QR + e) = make_uint2(lo, hi);
}

// ---------------- V transpose to bf16: VT[b][d][t] ----------------
__global__ void vt_kernel(const float* __restrict__ V, uint16_t* __restrict__ VT) {
  int o = blockIdx.x * 256 + threadIdx.x;                    // < 2^20
  int t = o & (Tn - 1);
  int d = (o >> 11) & (Dn - 1);
  int b = o >> 19;
  VT[o] = f2bf(V[((size_t)b * Tn + t) * Dn + d]);
}

// ---------------- masked QK^T * V, bf16 MFMA, 2-phase pipelined ----------------
__global__ __launch_bounds__(512) void attn_kernel(const uint16_t* __restrict__ QR,
                                                   const uint16_t* __restrict__ VT,
                                                   float* __restrict__ O) {
  const int bx = blockIdx.x;
  // XCD chunking: grid 1088 = 8 XCD-chunks of 136; XCD x (bx&7) owns head x.
  const int bh = bx & 7;
  int rem = bx >> 3;                       // tile pair index 0..135
  int tt = 0;
  while (rem > tt) { rem -= tt + 1; ++tt; }
  const int st = rem;
  const int b = bh >> 2;                   // H = 4

  const int tid = threadIdx.x;
  const int w = tid >> 6;
  const int l = tid & 63;
  const int l15 = l & 15;
  const int lg = l >> 4;

  // QK wave grid over ST (128 j x 128 i): 2 x 4
  const int wj = w >> 2;
  const int wi = w & 3;
  // PV wave grid over OT (256 d x 128 i): 4 x 2
  const int wd = w >> 1;
  const int wi2 = w & 1;

  // 64 KiB: two 32 KiB buffers (Qt 16K + Qs 16K each); S-tile aliases buf0.
  __shared__ __align__(16) char ldsB[65536];
  char* SlB = ldsB;

  const uint16_t* QRh = QR + (size_t)bh * Tn * Nn;

  const f32x4 zero = {0.f, 0.f, 0.f, 0.f};
  f32x4 oacc[4][4];
#pragma unroll
  for (int m = 0; m < 4; ++m)
#pragma unroll
    for (int n = 0; n < 4; ++n) oacc[m][n] = zero;

  f32x4 sacc[4][2];
#pragma unroll
  for (int m = 0; m < 4; ++m) { sacc[m][0] = zero; sacc[m][1] = zero; }

  // staging: linear LDS dest, inverse-swizzled global source (chunk XOR by row&7)
  const int srow = tid >> 3;                 // 0..63
  const int scg = (tid & 7) ^ (srow & 7);

  const uint16_t* gQt0 = QRh + (size_t)(tt * 128 + srow) * Nn + scg * 8;
  const uint16_t* gQt1 = QRh + (size_t)(tt * 128 + 64 + srow) * Nn + scg * 8;
  const uint16_t* gQs0 = QRh + (size_t)(st * 128 + srow) * Nn + scg * 8;
  const uint16_t* gQs1 = QRh + (size_t)(st * 128 + 64 + srow) * Nn + scg * 8;

#define STAGE(ke, bsel)                                              \
  do {                                                               \
    char* qt_ = ldsB + (bsel) * 32768;                               \
    char* qs_ = qt_ + 16384;                                         \
    gload_lds16(gQt0 + (ke), qt_ + w * 1024);                        \
    gload_lds16(gQt1 + (ke), qt_ + 8192 + w * 1024);                 \
    gload_lds16(gQs0 + (ke), qs_ + w * 1024);                        \
    gload_lds16(gQs1 + (ke), qs_ + 8192 + w * 1024);                 \
  } while (0)

  // prologue
  STAGE(0, 0);
  asm volatile("s_waitcnt vmcnt(0)" ::: "memory");
  __builtin_amdgcn_s_barrier();

  int cur = 0;
  for (int k0 = 0; k0 < NK; ++k0) {
    if (k0 + 1 < NK) STAGE((k0 + 1) * 64, cur ^ 1);
    const char* qtb = ldsB + cur * 32768;
    const char* qsb = qtb + 16384;
#pragma unroll
    for (int ks = 0; ks < 2; ++ks) {
      short8 a[4], bb[2];
#pragma unroll
      for (int m = 0; m < 4; ++m) {
        int row = wj * 64 + m * 16 + l15;                       // j row
        int c = (4 * ks + lg) ^ (row & 7);
        a[m] = *(const short8*)(qsb + row * 128 + c * 16);
      }
#pragma unroll
      for (int n = 0; n < 2; ++n) {
        int row = wi * 32 + n * 16 + l15;                       // i row
        int c = (4 * ks + lg) ^ (row & 7);
        bb[n] = *(const short8*)(qtb + row * 128 + c * 16);
      }
#pragma unroll
      for (int m = 0; m < 4; ++m)
#pragma unroll
        for (int n = 0; n < 2; ++n)
          sacc[m][n] = __builtin_amdgcn_mfma_f32_16x16x32_bf16(a[m], bb[n], sacc[m][n], 0, 0, 0);
    }
    asm volatile("s_waitcnt vmcnt(0)" ::: "memory");   // next tile's loads landed
    __builtin_amdgcn_s_barrier();
    cur ^= 1;
  }

  // mask (strict causal: keep j < i on diagonal tile) + pack ST -> Sl[i][j] (aliases buf0)
  const bool diag = (st == tt);
#pragma unroll
  for (int m = 0; m < 4; ++m)
#pragma unroll
    for (int n = 0; n < 2; ++n) {
      int j0 = wj * 64 + m * 16 + lg * 4;    // 4 consecutive j (C/D rows)
      int i = wi * 32 + n * 16 + l15;        // C/D col
      f32x4 v = sacc[m][n];
      if (diag) {
#pragma unroll
        for (int rr = 0; rr < 4; ++rr)
          if (j0 + rr >= i) v[rr] = 0.f;
      }
      uint32_t lo = (uint32_t)f2bf(v[0]) | ((uint32_t)f2bf(v[1]) << 16);
      uint32_t hi = (uint32_t)f2bf(v[2]) | ((uint32_t)f2bf(v[3]) << 16);
      int byte = i * 256 + ((2 * j0) ^ ((i & 15) << 4));
      *(uint2*)(SlB + byte) = make_uint2(lo, hi);
    }
  __syncthreads();

  // PV: OT[d][i] += sum_j VT[d][j] * S[i][j]
#pragma unroll
  for (int kc = 0; kc < 4; ++kc) {
    short8 av[4], bv[4];
#pragma unroll
    for (int m2 = 0; m2 < 4; ++m2) {
      int d = wd * 64 + m2 * 16 + l15;
      av[m2] = *(const short8*)(VT + (size_t)(b * Dn + d) * Tn + (size_t)st * 128 + kc * 32 + lg * 8);
    }
#pragma unroll
    for (int n2 = 0; n2 < 4; ++n2) {
      int i = wi2 * 64 + n2 * 16 + l15;
      int j = kc * 32 + lg * 8;
      int byte = i * 256 + ((2 * j) ^ ((i & 15) << 4));
      bv[n2] = *(const short8*)(SlB + byte);
    }
#pragma unroll
    for (int m2 = 0; m2 < 4; ++m2)
#pragma unroll
      for (int n2 = 0; n2 < 4; ++n2)
        oacc[m2][n2] = __builtin_amdgcn_mfma_f32_16x16x32_bf16(av[m2], bv[n2], oacc[m2][n2], 0, 0, 0);
  }

  // combine partial O via atomics (O was zeroed by hipMemsetAsync)
  float* Obh = O + ((size_t)bh * Tn + (size_t)tt * 128) * Dn;
#pragma unroll
  for (int m2 = 0; m2 < 4; ++m2)
#pragma unroll
    for (int n2 = 0; n2 < 4; ++n2) {
      int dbase = wd * 64 + m2 * 16 + lg * 4;
      int i = wi2 * 64 + n2 * 16 + l15;
#pragma unroll
      for (int rr = 0; rr < 4; ++rr)
        atomicAdd(Obh + (size_t)i * Dn + dbase + rr, oacc[m2][n2][rr]);
    }
}

extern "C" void kernel_launch(void* const* d_in, const int* in_sizes, int n_in,
                              void* d_out, int out_size, void* d_ws, size_t ws_size,
                              hipStream_t stream) {
  const float* Q = (const float*)d_in[0];
  const float* V = (const float*)d_in[1];
  float* O = (float*)d_out;

  uint16_t* QRw = (uint16_t*)d_ws;                       // 64 MiB bf16 QR
  uint16_t* VTw = QRw + (size_t)BH * Tn * Nn;            // 2 MiB bf16 V^T

  hipMemsetAsync(d_out, 0, (size_t)out_size * sizeof(float), stream);
  rope_kernel<<<(BH * (size_t)Tn * Nn / 4) / 256, 256, 0, stream>>>(Q, QRw);
  vt_kernel<<<(Bn * Dn * Tn) / 256, 256, 0, stream>>>(V, VTw);
  attn_kernel<<<BH * NP, 512, 0, stream>>>(QRw, VTw, O);
}

// Round 3
// 220.816 us; speedup vs baseline: 2.5294x; 2.5294x over previous
//
#include <hip/hip_runtime.h>
#include <stdint.h>

#define Tn 2048
#define Nn 2048
#define Dn 256
#define HB 4              // heads per batch
#define NK1 32            // K-steps of 64 over N=2048

typedef __attribute__((ext_vector_type(8))) short short8;
typedef __attribute__((ext_vector_type(4))) float f32x4;

__device__ __forceinline__ uint16_t f2bf(float x) {
  uint32_t u = __float_as_uint(x);
  return (uint16_t)((u + 0x7FFFu + ((u >> 16) & 1u)) >> 16);   // RNE
}

__device__ __forceinline__ void gload_lds16(const void* g, void* l) {
  __builtin_amdgcn_global_load_lds((const __attribute__((address_space(1))) uint32_t*)g,
                                   (__attribute__((address_space(3))) uint32_t*)l,
                                   16, 0, 0);
}

// ---------------- RoPE + bf16 cast for one batch: Qb[4][T][N] -> QR[4][T][N] ----------------
__global__ void rope_kernel(const float* __restrict__ Qb, uint16_t* __restrict__ QR) {
  size_t e = ((size_t)blockIdx.x * 256 + threadIdx.x) * 4;
  int n = (int)(e & (Nn - 1));
  int t = (int)((e >> 11) & (Tn - 1));
  const float4 q = *(const float4*)(Qb + e);
  int p0 = n >> 1;
  float f0 = exp2f(-(float)p0 * (1.0f / 64.0f)) * 0.15915494309189535f;
  float f1 = exp2f(-(float)(p0 + 1) * (1.0f / 64.0f)) * 0.15915494309189535f;
  float x0 = (float)t * f0, x1 = (float)t * f1;
  float r0 = x0 - floorf(x0), r1 = x1 - floorf(x1);            // revolutions
  float s0 = __builtin_amdgcn_sinf(r0), c0 = __builtin_amdgcn_cosf(r0);
  float s1 = __builtin_amdgcn_sinf(r1), c1 = __builtin_amdgcn_cosf(r1);
  float o0 = q.x * c0 - q.y * s0;
  float o1 = q.y * c0 + q.x * s0;
  float o2 = q.z * c1 - q.w * s1;
  float o3 = q.w * c1 + q.z * s1;
  uint32_t lo = (uint32_t)f2bf(o0) | ((uint32_t)f2bf(o1) << 16);
  uint32_t hi = (uint32_t)f2bf(o2) | ((uint32_t)f2bf(o3) << 16);
  *(uint2*)(QR + e) = make_uint2(lo, hi);
}

// ---------------- V transpose to bf16: VT[b][d][t] ----------------
__global__ void vt_kernel(const float* __restrict__ V, uint16_t* __restrict__ VT) {
  int o = blockIdx.x * 256 + threadIdx.x;
  int t = o & (Tn - 1);
  int d = (o >> 11) & (Dn - 1);
  int b = o >> 19;
  VT[o] = f2bf(V[((size_t)b * Tn + t) * Dn + d]);
}

// ---------------- K1: S = tril(QR QR^T) bf16, 256x256 tiles, 2-phase pipelined ----------------
// grid 144: blocks 0..111 off-diag (hh = bx&3, pair idx bx>>3... bx>>2), 112..143 diagonal
__global__ __launch_bounds__(512) void qkt_kernel(const uint16_t* __restrict__ QR,
                                                  uint16_t* __restrict__ S) {
  extern __shared__ char lds[];
  const int bx = blockIdx.x;
  int hh, ti, tj; bool diag;
  if (bx < 112) {
    hh = bx & 3;
    int p = bx >> 2;                 // 0..27
    ti = 1; while (p >= ti) { p -= ti; ++ti; }
    tj = p; diag = false;
  } else {
    int d2 = bx - 112;               // 0..31
    hh = d2 & 3; ti = d2 >> 2; tj = ti; diag = true;
  }
  const int tid = threadIdx.x;
  const int w = tid >> 6, l = tid & 63, l15 = l & 15, lg = l >> 4;
  const int ih = w >> 2;             // i half (128 rows)
  const int jq = w & 3;              // j quarter (64 cols)
  const bool active = !(diag && ih == 0 && jq >= 2);   // skip fully-masked waves on diag

  const uint16_t* QRh = QR + (size_t)hh * Tn * Nn;
  const int r0 = tid >> 3;                       // staging row 0..63
  const int scg = (tid & 7) ^ (r0 & 7);          // inverse-swizzled source chunk
  const uint16_t* gB = QRh + (size_t)(ti * 256 + r0) * Nn + scg * 8;   // i-side panel
  const uint16_t* gA = QRh + (size_t)(tj * 256 + r0) * Nn + scg * 8;   // j-side panel

  f32x4 acc[8][4];
#pragma unroll
  for (int mi = 0; mi < 8; ++mi)
#pragma unroll
    for (int nj = 0; nj < 4; ++nj) acc[mi][nj] = (f32x4){0.f, 0.f, 0.f, 0.f};

  auto stage = [&](int ke, int bsel) {
    char* bufB = lds + bsel * 65536;
    char* bufA = bufB + 32768;
#pragma unroll
    for (int rnd = 0; rnd < 4; ++rnd) {
      gload_lds16(gB + (size_t)rnd * 64 * Nn + ke, bufB + rnd * 8192 + w * 1024);
      if (!diag) gload_lds16(gA + (size_t)rnd * 64 * Nn + ke, bufA + rnd * 8192 + w * 1024);
    }
  };

  stage(0, 0);
  asm volatile("s_waitcnt vmcnt(0)" ::: "memory");
  __builtin_amdgcn_s_barrier();

  int cur = 0;
  for (int k0 = 0; k0 < NK1; ++k0) {
    if (k0 + 1 < NK1) stage((k0 + 1) * 64, cur ^ 1);
    const char* bB = lds + cur * 65536;
    const char* bA = diag ? bB : bB + 32768;
    if (active) {
#pragma unroll
      for (int ks = 0; ks < 2; ++ks) {
        short8 bfr[8], afr[4];
#pragma unroll
        for (int mi = 0; mi < 8; ++mi) {
          int row = ih * 128 + mi * 16 + l15;
          int c = (ks * 4 + lg) ^ (row & 7);
          bfr[mi] = *(const short8*)(bB + row * 128 + c * 16);
        }
#pragma unroll
        for (int nj = 0; nj < 4; ++nj) {
          int row = jq * 64 + nj * 16 + l15;
          int c = (ks * 4 + lg) ^ (row & 7);
          afr[nj] = *(const short8*)(bA + row * 128 + c * 16);
        }
#pragma unroll
        for (int mi = 0; mi < 8; ++mi)
#pragma unroll
          for (int nj = 0; nj < 4; ++nj)
            acc[mi][nj] = __builtin_amdgcn_mfma_f32_16x16x32_bf16(afr[nj], bfr[mi], acc[mi][nj], 0, 0, 0);
      }
    }
    asm volatile("s_waitcnt vmcnt(0)" ::: "memory");
    __builtin_amdgcn_s_barrier();
    cur ^= 1;
  }

  // store (masked on diag): C/D col = i (l15), rows = j (lg*4+rr)
  uint16_t* Sh = S + (size_t)hh * Tn * Tn;
#pragma unroll
  for (int mi = 0; mi < 8; ++mi)
#pragma unroll
    for (int nj = 0; nj < 4; ++nj) {
      int iloc = ih * 128 + mi * 16 + l15;
      int jloc = jq * 64 + nj * 16 + lg * 4;
      f32x4 v = acc[mi][nj];
      if (diag) {
#pragma unroll
        for (int rr = 0; rr < 4; ++rr)
          if (jloc + rr >= iloc) v[rr] = 0.f;
      }
      uint32_t lo = (uint32_t)f2bf(v[0]) | ((uint32_t)f2bf(v[1]) << 16);
      uint32_t hi = (uint32_t)f2bf(v[2]) | ((uint32_t)f2bf(v[3]) << 16);
      *(uint2*)(Sh + (size_t)(ti * 256 + iloc) * Tn + tj * 256 + jloc) = make_uint2(lo, hi);
    }
}

// ---------------- K2: O = S * V (via VT), 128x256 tiles ----------------
// grid 64 per batch: hh = bx&3, ti = bx>>2 (0..15)
__global__ __launch_bounds__(512) void pv_kernel(const uint16_t* __restrict__ S,
                                                 const uint16_t* __restrict__ VT,
                                                 float* __restrict__ O, int b) {
  extern __shared__ char lds[];
  const int bx = blockIdx.x;
  const int hh = bx & 3, ti = bx >> 2;
  const int nsteps = 2 * ti + 2;

  const int tid = threadIdx.x;
  const int w = tid >> 6, l = tid & 63, l15 = l & 15, lg = l >> 4;
  const int ih = w >> 2;             // i half (64 rows of 128)
  const int dq = w & 3;              // d quarter (64 of 256)

  const uint16_t* Sh = S + (size_t)hh * Tn * Tn;
  const uint16_t* VTb = VT + (size_t)b * Dn * Tn;
  const int r0 = tid >> 3;
  const int scg = (tid & 7) ^ (r0 & 7);
  const uint16_t* gS = Sh + (size_t)(ti * 128 + r0) * Tn + scg * 8;
  const uint16_t* gV = VTb + (size_t)r0 * Tn + scg * 8;

  f32x4 acc[4][4];
#pragma unroll
  for (int ma = 0; ma < 4; ++ma)
#pragma unroll
    for (int ni = 0; ni < 4; ++ni) acc[ma][ni] = (f32x4){0.f, 0.f, 0.f, 0.f};

  auto stage = [&](int ke, int bsel) {
    char* bufS = lds + bsel * 49152;
    char* bufV = bufS + 16384;
#pragma unroll
    for (int rnd = 0; rnd < 2; ++rnd)
      gload_lds16(gS + (size_t)rnd * 64 * Tn + ke, bufS + rnd * 8192 + w * 1024);
#pragma unroll
    for (int rnd = 0; rnd < 4; ++rnd)
      gload_lds16(gV + (size_t)rnd * 64 * Tn + ke, bufV + rnd * 8192 + w * 1024);
  };

  stage(0, 0);
  asm volatile("s_waitcnt vmcnt(0)" ::: "memory");
  __builtin_amdgcn_s_barrier();

  int cur = 0;
  for (int jt = 0; jt < nsteps; ++jt) {
    if (jt + 1 < nsteps) stage((jt + 1) * 64, cur ^ 1);
    const char* bS = lds + cur * 49152;
    const char* bV = bS + 16384;
#pragma unroll
    for (int ks = 0; ks < 2; ++ks) {
      short8 av[4], bs[4];
#pragma unroll
      for (int ma = 0; ma < 4; ++ma) {
        int row = dq * 64 + ma * 16 + l15;       // d row in VT panel (256 rows)
        int c = (ks * 4 + lg) ^ (row & 7);
        av[ma] = *(const short8*)(bV + row * 128 + c * 16);
      }
#pragma unroll
      for (int ni = 0; ni < 4; ++ni) {
        int row = ih * 64 + ni * 16 + l15;       // i row in S panel (128 rows)
        int c = (ks * 4 + lg) ^ (row & 7);
        bs[ni] = *(const short8*)(bS + row * 128 + c * 16);
      }
#pragma unroll
      for (int ma = 0; ma < 4; ++ma)
#pragma unroll
        for (int ni = 0; ni < 4; ++ni)
          acc[ma][ni] = __builtin_amdgcn_mfma_f32_16x16x32_bf16(av[ma], bs[ni], acc[ma][ni], 0, 0, 0);
    }
    asm volatile("s_waitcnt vmcnt(0)" ::: "memory");
    __builtin_amdgcn_s_barrier();
    cur ^= 1;
  }

  // store: col(l15) = i, rows(lg*4+rr) = d -> 16B fp32 stores
  float* Oh = O + (size_t)(b * HB + hh) * Tn * Dn;
#pragma unroll
  for (int ma = 0; ma < 4; ++ma)
#pragma unroll
    for (int ni = 0; ni < 4; ++ni) {
      int iloc = ih * 64 + ni * 16 + l15;
      int d0 = dq * 64 + ma * 16 + lg * 4;
      *(f32x4*)(Oh + (size_t)(ti * 128 + iloc) * Dn + d0) = acc[ma][ni];
    }
}

extern "C" void kernel_launch(void* const* d_in, const int* in_sizes, int n_in,
                              void* d_out, int out_size, void* d_ws, size_t ws_size,
                              hipStream_t stream) {
  const float* Q = (const float*)d_in[0];
  const float* V = (const float*)d_in[1];
  float* O = (float*)d_out;

  // ws: QR bf16 [4][T][N] (32 MiB) | VT bf16 [2][D][T] (2 MiB) | S bf16 [4][T][T] (32 MiB)
  uint16_t* QRw = (uint16_t*)d_ws;
  uint16_t* VTw = QRw + (size_t)HB * Tn * Nn;
  uint16_t* Sw  = VTw + (size_t)2 * Dn * Tn;

  hipFuncSetAttribute((const void*)qkt_kernel, hipFuncAttributeMaxDynamicSharedMemorySize, 131072);
  hipFuncSetAttribute((const void*)pv_kernel,  hipFuncAttributeMaxDynamicSharedMemorySize, 98304);

  vt_kernel<<<(2 * Dn * Tn) / 256, 256, 0, stream>>>(V, VTw);
  for (int b = 0; b < 2; ++b) {
    rope_kernel<<<((size_t)HB * Tn * Nn / 4) / 256, 256, 0, stream>>>(Q + (size_t)b * HB * Tn * Nn, QRw);
    qkt_kernel<<<144, 512, 131072, stream>>>(QRw, Sw);
    pv_kernel<<<64, 512, 98304, stream>>>(Sw, VTw, O, b);
  }
}

// Round 4
// 168.653 us; speedup vs baseline: 3.3118x; 1.3093x over previous
//
#include <hip/hip_runtime.h>
#include <stdint.h>

#define Tn 2048
#define Nn 2048
#define Dn 256
#define NHEAD 8           // flattened b*4+h
#define NK1 32            // K-steps of 64 over N=2048

typedef __attribute__((ext_vector_type(8))) short short8;
typedef __attribute__((ext_vector_type(4))) float f32x4;

__device__ __forceinline__ uint16_t f2bf(float x) {
  uint32_t u = __float_as_uint(x);
  return (uint16_t)((u + 0x7FFFu + ((u >> 16) & 1u)) >> 16);   // RNE
}

__device__ __forceinline__ void gload_lds16(const void* g, void* l) {
  __builtin_amdgcn_global_load_lds((const __attribute__((address_space(1))) uint32_t*)g,
                                   (__attribute__((address_space(3))) uint32_t*)l,
                                   16, 0, 0);
}

// ---------------- RoPE + bf16 cast, all heads: Q[8][T][N] -> QR[8][T][N] ----------------
__global__ void rope_kernel(const float* __restrict__ Q, uint16_t* __restrict__ QR) {
  size_t e = ((size_t)blockIdx.x * 256 + threadIdx.x) * 4;
  int n = (int)(e & (Nn - 1));
  int t = (int)((e >> 11) & (Tn - 1));
  const float4 q = *(const float4*)(Q + e);
  int p0 = n >> 1;
  float f0 = exp2f(-(float)p0 * (1.0f / 64.0f)) * 0.15915494309189535f;
  float f1 = exp2f(-(float)(p0 + 1) * (1.0f / 64.0f)) * 0.15915494309189535f;
  float x0 = (float)t * f0, x1 = (float)t * f1;
  float r0 = x0 - floorf(x0), r1 = x1 - floorf(x1);            // revolutions
  float s0 = __builtin_amdgcn_sinf(r0), c0 = __builtin_amdgcn_cosf(r0);
  float s1 = __builtin_amdgcn_sinf(r1), c1 = __builtin_amdgcn_cosf(r1);
  float o0 = q.x * c0 - q.y * s0;
  float o1 = q.y * c0 + q.x * s0;
  float o2 = q.z * c1 - q.w * s1;
  float o3 = q.w * c1 + q.z * s1;
  uint32_t lo = (uint32_t)f2bf(o0) | ((uint32_t)f2bf(o1) << 16);
  uint32_t hi = (uint32_t)f2bf(o2) | ((uint32_t)f2bf(o3) << 16);
  *(uint2*)(QR + e) = make_uint2(lo, hi);
}

// ---------------- V transpose to bf16: VT[b][d][t] ----------------
__global__ void vt_kernel(const float* __restrict__ V, uint16_t* __restrict__ VT) {
  int o = blockIdx.x * 256 + threadIdx.x;
  int t = o & (Tn - 1);
  int d = (o >> 11) & (Dn - 1);
  int b = o >> 19;
  VT[o] = f2bf(V[((size_t)b * Tn + t) * Dn + d]);
}

// ---------------- K1: S = tril(QR QR^T) bf16, 256x256 tiles, 2-phase pipelined ----------------
// grid 288: xcd = bx&7 = head g; job p = bx>>3: p<28 off-diag (grouped by ti), p>=28 diag
__global__ __launch_bounds__(512) void qkt_kernel(const uint16_t* __restrict__ QR,
                                                  uint16_t* __restrict__ S) {
  extern __shared__ char lds[];
  const int bx = blockIdx.x;
  const int g = bx & 7;
  int p = bx >> 3;                   // 0..35
  int ti, tj; bool diag;
  if (p < 28) {
    ti = 1; while (p >= ti) { p -= ti; ++ti; }
    tj = p; diag = false;
  } else {
    ti = p - 28; tj = ti; diag = true;
  }
  const int tid = threadIdx.x;
  const int w = tid >> 6, l = tid & 63, l15 = l & 15, lg = l >> 4;
  const int ih = w >> 2;             // i half (128 rows)
  const int jq = w & 3;              // j quarter (64 cols)
  const bool active = !(diag && ih == 0 && jq >= 2);   // fully-masked waves on diag

  const uint16_t* QRh = QR + (size_t)g * Tn * Nn;
  const int r0 = tid >> 3;                       // staging row 0..63
  const int scg = (tid & 7) ^ (r0 & 7);          // inverse-swizzled source chunk
  const uint16_t* gB = QRh + (size_t)(ti * 256 + r0) * Nn + scg * 8;   // i-side panel
  const uint16_t* gA = QRh + (size_t)(tj * 256 + r0) * Nn + scg * 8;   // j-side panel

  f32x4 acc[8][4];
#pragma unroll
  for (int mi = 0; mi < 8; ++mi)
#pragma unroll
    for (int nj = 0; nj < 4; ++nj) acc[mi][nj] = (f32x4){0.f, 0.f, 0.f, 0.f};

  auto stage = [&](int ke, int bsel) {
    char* bufB = lds + bsel * 65536;
    char* bufA = bufB + 32768;
#pragma unroll
    for (int rnd = 0; rnd < 4; ++rnd) {
      gload_lds16(gB + (size_t)rnd * 64 * Nn + ke, bufB + rnd * 8192 + w * 1024);
      if (!diag) gload_lds16(gA + (size_t)rnd * 64 * Nn + ke, bufA + rnd * 8192 + w * 1024);
    }
  };

  stage(0, 0);
  asm volatile("s_waitcnt vmcnt(0)" ::: "memory");
  __builtin_amdgcn_s_barrier();

  int cur = 0;
  for (int k0 = 0; k0 < NK1; ++k0) {
    if (k0 + 1 < NK1) stage((k0 + 1) * 64, cur ^ 1);
    const char* bB = lds + cur * 65536;
    const char* bA = diag ? bB : bB + 32768;
    if (active) {
#pragma unroll
      for (int ks = 0; ks < 2; ++ks) {
        short8 bfr[8], afr[4];
#pragma unroll
        for (int mi = 0; mi < 8; ++mi) {
          int row = ih * 128 + mi * 16 + l15;
          int c = (ks * 4 + lg) ^ (row & 7);
          bfr[mi] = *(const short8*)(bB + row * 128 + c * 16);
        }
#pragma unroll
        for (int nj = 0; nj < 4; ++nj) {
          int row = jq * 64 + nj * 16 + l15;
          int c = (ks * 4 + lg) ^ (row & 7);
          afr[nj] = *(const short8*)(bA + row * 128 + c * 16);
        }
#pragma unroll
        for (int mi = 0; mi < 8; ++mi)
#pragma unroll
          for (int nj = 0; nj < 4; ++nj)
            acc[mi][nj] = __builtin_amdgcn_mfma_f32_16x16x32_bf16(afr[nj], bfr[mi], acc[mi][nj], 0, 0, 0);
      }
    }
    asm volatile("s_waitcnt vmcnt(0)" ::: "memory");
    __builtin_amdgcn_s_barrier();
    cur ^= 1;
  }

  // store (masked on diag): C/D col = i (l15), rows = j (lg*4+rr)
  uint16_t* Sh = S + (size_t)g * Tn * Tn;
#pragma unroll
  for (int mi = 0; mi < 8; ++mi)
#pragma unroll
    for (int nj = 0; nj < 4; ++nj) {
      int iloc = ih * 128 + mi * 16 + l15;
      int jloc = jq * 64 + nj * 16 + lg * 4;
      f32x4 v = acc[mi][nj];
      if (diag) {
#pragma unroll
        for (int rr = 0; rr < 4; ++rr)
          if (jloc + rr >= iloc) v[rr] = 0.f;
      }
      uint32_t lo = (uint32_t)f2bf(v[0]) | ((uint32_t)f2bf(v[1]) << 16);
      uint32_t hi = (uint32_t)f2bf(v[2]) | ((uint32_t)f2bf(v[3]) << 16);
      *(uint2*)(Sh + (size_t)(ti * 256 + iloc) * Tn + tj * 256 + jloc) = make_uint2(lo, hi);
    }
}

// ---------------- K2: O = S * V (via VT), 128 i x 128 d tiles, both batches ----------------
// grid 256: xcd = bx&7 = head g; j2 = bx>>3: ti = 15-(j2>>1) (longest first), dh = j2&1
__global__ __launch_bounds__(512) void pv_kernel(const uint16_t* __restrict__ S,
                                                 const uint16_t* __restrict__ VT,
                                                 float* __restrict__ O) {
  extern __shared__ char lds[];
  const int bx = blockIdx.x;
  const int g = bx & 7;
  const int b = g >> 2;
  const int j2 = bx >> 3;            // 0..31
  const int ti = 15 - (j2 >> 1);
  const int dh = j2 & 1;
  const int nsteps = 2 * ti + 2;

  const int tid = threadIdx.x;
  const int w = tid >> 6, l = tid & 63, l15 = l & 15, lg = l >> 4;
  const int ih = w >> 2;             // i half (64 rows of 128)
  const int dq = w & 3;              // d quarter (32 of 128)

  const uint16_t* Sh = S + (size_t)g * Tn * Tn;
  const uint16_t* VTb = VT + (size_t)b * Dn * Tn;
  const int r0 = tid >> 3;
  const int scg = (tid & 7) ^ (r0 & 7);
  const uint16_t* gS = Sh + (size_t)(ti * 128 + r0) * Tn + scg * 8;
  const uint16_t* gV = VTb + (size_t)(dh * 128 + r0) * Tn + scg * 8;

  f32x4 acc[2][4];
#pragma unroll
  for (int ma = 0; ma < 2; ++ma)
#pragma unroll
    for (int ni = 0; ni < 4; ++ni) acc[ma][ni] = (f32x4){0.f, 0.f, 0.f, 0.f};

  auto stage = [&](int ke, int bsel) {
    char* bufS = lds + bsel * 32768;
    char* bufV = bufS + 16384;
#pragma unroll
    for (int rnd = 0; rnd < 2; ++rnd) {
      gload_lds16(gS + (size_t)rnd * 64 * Tn + ke, bufS + rnd * 8192 + w * 1024);
      gload_lds16(gV + (size_t)rnd * 64 * Tn + ke, bufV + rnd * 8192 + w * 1024);
    }
  };

  stage(0, 0);
  asm volatile("s_waitcnt vmcnt(0)" ::: "memory");
  __builtin_amdgcn_s_barrier();

  int cur = 0;
  for (int jt = 0; jt < nsteps; ++jt) {
    if (jt + 1 < nsteps) stage((jt + 1) * 64, cur ^ 1);
    const char* bS = lds + cur * 32768;
    const char* bV = bS + 16384;
#pragma unroll
    for (int ks = 0; ks < 2; ++ks) {
      short8 av[2], bs[4];
#pragma unroll
      for (int ma = 0; ma < 2; ++ma) {
        int row = dq * 32 + ma * 16 + l15;       // local d row (128)
        int c = (ks * 4 + lg) ^ (row & 7);
        av[ma] = *(const short8*)(bV + row * 128 + c * 16);
      }
#pragma unroll
      for (int ni = 0; ni < 4; ++ni) {
        int row = ih * 64 + ni * 16 + l15;       // local i row (128)
        int c = (ks * 4 + lg) ^ (row & 7);
        bs[ni] = *(const short8*)(bS + row * 128 + c * 16);
      }
#pragma unroll
      for (int ma = 0; ma < 2; ++ma)
#pragma unroll
        for (int ni = 0; ni < 4; ++ni)
          acc[ma][ni] = __builtin_amdgcn_mfma_f32_16x16x32_bf16(av[ma], bs[ni], acc[ma][ni], 0, 0, 0);
    }
    asm volatile("s_waitcnt vmcnt(0)" ::: "memory");
    __builtin_amdgcn_s_barrier();
    cur ^= 1;
  }

  // store: col(l15) = i, rows(lg*4+rr) = d -> 16B fp32 stores
  float* Oh = O + (size_t)g * Tn * Dn;
#pragma unroll
  for (int ma = 0; ma < 2; ++ma)
#pragma unroll
    for (int ni = 0; ni < 4; ++ni) {
      int iloc = ih * 64 + ni * 16 + l15;
      int d0 = dh * 128 + dq * 32 + ma * 16 + lg * 4;
      *(f32x4*)(Oh + (size_t)(ti * 128 + iloc) * Dn + d0) = acc[ma][ni];
    }
}

extern "C" void kernel_launch(void* const* d_in, const int* in_sizes, int n_in,
                              void* d_out, int out_size, void* d_ws, size_t ws_size,
                              hipStream_t stream) {
  const float* Q = (const float*)d_in[0];
  const float* V = (const float*)d_in[1];
  float* O = (float*)d_out;

  // ws: QR bf16 [8][T][N] (64 MiB) | VT bf16 [2][D][T] (2 MiB) | S bf16 [8][T][T] (64 MiB)
  uint16_t* QRw = (uint16_t*)d_ws;
  uint16_t* VTw = QRw + (size_t)NHEAD * Tn * Nn;
  uint16_t* Sw  = VTw + (size_t)2 * Dn * Tn;

  hipFuncSetAttribute((const void*)qkt_kernel, hipFuncAttributeMaxDynamicSharedMemorySize, 131072);
  hipFuncSetAttribute((const void*)pv_kernel,  hipFuncAttributeMaxDynamicSharedMemorySize, 65536);

  rope_kernel<<<((size_t)NHEAD * Tn * Nn / 4) / 256, 256, 0, stream>>>(Q, QRw);
  vt_kernel<<<(2 * Dn * Tn) / 256, 256, 0, stream>>>(V, VTw);
  qkt_kernel<<<288, 512, 131072, stream>>>(QRw, Sw);
  pv_kernel<<<256, 512, 65536, stream>>>(Sw, VTw, O);
}

// Round 5
// 150.982 us; speedup vs baseline: 3.6994x; 1.1170x over previous
//
#include <hip/hip_runtime.h>
#include <stdint.h>

#define Tn 2048
#define Nn 2048
#define Dn 256
#define NHEAD 8           // flattened b*4+h
#define NK1 32            // K-steps of 64 over N=2048

typedef __attribute__((ext_vector_type(8))) short short8;
typedef __attribute__((ext_vector_type(4))) float f32x4;

__device__ __forceinline__ uint16_t f2bf(float x) {
  uint32_t u = __float_as_uint(x);
  return (uint16_t)((u + 0x7FFFu + ((u >> 16) & 1u)) >> 16);   // RNE
}

__device__ __forceinline__ void gload_lds16(const void* g, void* l) {
  __builtin_amdgcn_global_load_lds((const __attribute__((address_space(1))) uint32_t*)g,
                                   (__attribute__((address_space(3))) uint32_t*)l,
                                   16, 0, 0);
}

// ---------------- RoPE + bf16 cast, all heads: Q[8][T][N] -> QR[8][T][N] ----------------
__global__ void rope_kernel(const float* __restrict__ Q, uint16_t* __restrict__ QR) {
  size_t e = ((size_t)blockIdx.x * 256 + threadIdx.x) * 4;
  int n = (int)(e & (Nn - 1));
  int t = (int)((e >> 11) & (Tn - 1));
  const float4 q = *(const float4*)(Q + e);
  int p0 = n >> 1;
  float f0 = exp2f(-(float)p0 * (1.0f / 64.0f)) * 0.15915494309189535f;
  float f1 = exp2f(-(float)(p0 + 1) * (1.0f / 64.0f)) * 0.15915494309189535f;
  float x0 = (float)t * f0, x1 = (float)t * f1;
  float r0 = x0 - floorf(x0), r1 = x1 - floorf(x1);            // revolutions
  float s0 = __builtin_amdgcn_sinf(r0), c0 = __builtin_amdgcn_cosf(r0);
  float s1 = __builtin_amdgcn_sinf(r1), c1 = __builtin_amdgcn_cosf(r1);
  float o0 = q.x * c0 - q.y * s0;
  float o1 = q.y * c0 + q.x * s0;
  float o2 = q.z * c1 - q.w * s1;
  float o3 = q.w * c1 + q.z * s1;
  uint32_t lo = (uint32_t)f2bf(o0) | ((uint32_t)f2bf(o1) << 16);
  uint32_t hi = (uint32_t)f2bf(o2) | ((uint32_t)f2bf(o3) << 16);
  *(uint2*)(QR + e) = make_uint2(lo, hi);
}

// ---------------- V transpose to bf16: VT[b][d][t] ----------------
__global__ void vt_kernel(const float* __restrict__ V, uint16_t* __restrict__ VT) {
  int o = blockIdx.x * 256 + threadIdx.x;
  int t = o & (Tn - 1);
  int d = (o >> 11) & (Dn - 1);
  int b = o >> 19;
  VT[o] = f2bf(V[((size_t)b * Tn + t) * Dn + d]);
}

// ---------------- K1: S = tril(QR QR^T) bf16, 128x128 tiles (m97 structure) ----------------
// grid 1088: xcd = bx&7 = head g; job p = bx>>3 (0..135):
//   p<120: off-diag (ti 1..15, tj<ti, grouped by ti); p>=120: diag ti=p-120 (cheap, last)
__global__ __launch_bounds__(256) void qkt_kernel(const uint16_t* __restrict__ QR,
                                                  uint16_t* __restrict__ S) {
  __shared__ __align__(16) char lds0[32768];   // I-panel 16K | J-panel 16K, single-buffered
  const int bx = blockIdx.x;
  const int g = bx & 7;
  int p = bx >> 3;
  int ti, tj; bool diag;
  if (p < 120) {
    ti = 1; while (p >= ti) { p -= ti; ++ti; }
    tj = p; diag = false;
  } else {
    ti = p - 120; tj = ti; diag = true;
  }

  const int tid = threadIdx.x;
  const int wv = tid >> 6, l = tid & 63, l15 = l & 15, lg = l >> 4;
  const int wi = wv >> 1;            // i half (64 rows)
  const int wj = wv & 1;             // j half (64 cols)
  const bool active = !(diag && wi == 0 && wj == 1);   // strict-upper wave on diag tile
  const bool needmask = diag && (wi == wj);

  const uint16_t* QRh = QR + (size_t)g * Tn * Nn;
  const int r0 = tid >> 3;                       // staging row 0..31
  const int scg = (tid & 7) ^ (r0 & 7);          // inverse-swizzled source chunk
  const uint16_t* gI = QRh + (size_t)(ti * 128 + r0) * Nn + scg * 8;
  const uint16_t* gJ = QRh + (size_t)(tj * 128 + r0) * Nn + scg * 8;

  char* bufI = lds0;
  char* bufJ = lds0 + 16384;

  f32x4 acc[4][4];
#pragma unroll
  for (int mi = 0; mi < 4; ++mi)
#pragma unroll
    for (int nj = 0; nj < 4; ++nj) acc[mi][nj] = (f32x4){0.f, 0.f, 0.f, 0.f};

  for (int k0 = 0; k0 < NK1; ++k0) {
    const int ke = k0 * 64;
    __syncthreads();                 // readers of previous tile done
#pragma unroll
    for (int rnd = 0; rnd < 4; ++rnd) {
      gload_lds16(gI + (size_t)rnd * 32 * Nn + ke, bufI + rnd * 4096 + wv * 1024);
      if (!diag) gload_lds16(gJ + (size_t)rnd * 32 * Nn + ke, bufJ + rnd * 4096 + wv * 1024);
    }
    __syncthreads();                 // staging landed (vmcnt drained by syncthreads)
    if (active) {
      const char* bI = bufI;
      const char* bJ = diag ? bufI : bufJ;
#pragma unroll
      for (int ks = 0; ks < 2; ++ks) {
        short8 ifr[4], jfr[4];
#pragma unroll
        for (int mi = 0; mi < 4; ++mi) {
          int row = wi * 64 + mi * 16 + l15;
          int c = (ks * 4 + lg) ^ (row & 7);
          ifr[mi] = *(const short8*)(bI + row * 128 + c * 16);
        }
#pragma unroll
        for (int nj = 0; nj < 4; ++nj) {
          int row = wj * 64 + nj * 16 + l15;
          int c = (ks * 4 + lg) ^ (row & 7);
          jfr[nj] = *(const short8*)(bJ + row * 128 + c * 16);
        }
#pragma unroll
        for (int mi = 0; mi < 4; ++mi)
#pragma unroll
          for (int nj = 0; nj < 4; ++nj)
            acc[mi][nj] = __builtin_amdgcn_mfma_f32_16x16x32_bf16(jfr[nj], ifr[mi], acc[mi][nj], 0, 0, 0);
      }
    }
  }

  // store (masked on diag): C/D col = i (l15), rows = j (lg*4+rr)
  uint16_t* Sh = S + (size_t)g * Tn * Tn;
  if (active) {
#pragma unroll
    for (int mi = 0; mi < 4; ++mi)
#pragma unroll
      for (int nj = 0; nj < 4; ++nj) {
        int iloc = wi * 64 + mi * 16 + l15;
        int jloc = wj * 64 + nj * 16 + lg * 4;
        f32x4 v = acc[mi][nj];
        if (needmask) {
#pragma unroll
          for (int rr = 0; rr < 4; ++rr)
            if (jloc + rr >= iloc) v[rr] = 0.f;
        }
        uint32_t lo = (uint32_t)f2bf(v[0]) | ((uint32_t)f2bf(v[1]) << 16);
        uint32_t hi = (uint32_t)f2bf(v[2]) | ((uint32_t)f2bf(v[3]) << 16);
        *(uint2*)(Sh + (size_t)(ti * 128 + iloc) * Tn + tj * 128 + jloc) = make_uint2(lo, hi);
      }
  } else {
    // fully-masked quadrant of diag tile: write zeros (S must be fully defined)
#pragma unroll
    for (int mi = 0; mi < 4; ++mi)
#pragma unroll
      for (int nj = 0; nj < 4; ++nj) {
        int iloc = wi * 64 + mi * 16 + l15;
        int jloc = wj * 64 + nj * 16 + lg * 4;
        *(uint2*)(Sh + (size_t)(ti * 128 + iloc) * Tn + tj * 128 + jloc) = make_uint2(0u, 0u);
      }
  }
}

// ---------------- K2: O = S * V (via VT), 128 i x 128 d tiles, both batches ----------------
// grid 256: xcd = bx&7 = head g; j2 = bx>>3: ti = 15-(j2>>1) (longest first), dh = j2&1
__global__ __launch_bounds__(512) void pv_kernel(const uint16_t* __restrict__ S,
                                                 const uint16_t* __restrict__ VT,
                                                 float* __restrict__ O) {
  extern __shared__ char lds[];
  const int bx = blockIdx.x;
  const int g = bx & 7;
  const int b = g >> 2;
  const int j2 = bx >> 3;            // 0..31
  const int ti = 15 - (j2 >> 1);
  const int dh = j2 & 1;
  const int nsteps = 2 * ti + 2;

  const int tid = threadIdx.x;
  const int w = tid >> 6, l = tid & 63, l15 = l & 15, lg = l >> 4;
  const int ih = w >> 2;             // i half (64 rows of 128)
  const int dq = w & 3;              // d quarter (32 of 128)

  const uint16_t* Sh = S + (size_t)g * Tn * Tn;
  const uint16_t* VTb = VT + (size_t)b * Dn * Tn;
  const int r0 = tid >> 3;
  const int scg = (tid & 7) ^ (r0 & 7);
  const uint16_t* gS = Sh + (size_t)(ti * 128 + r0) * Tn + scg * 8;
  const uint16_t* gV = VTb + (size_t)(dh * 128 + r0) * Tn + scg * 8;

  f32x4 acc[2][4];
#pragma unroll
  for (int ma = 0; ma < 2; ++ma)
#pragma unroll
    for (int ni = 0; ni < 4; ++ni) acc[ma][ni] = (f32x4){0.f, 0.f, 0.f, 0.f};

  auto stage = [&](int ke, int bsel) {
    char* bufS = lds + bsel * 32768;
    char* bufV = bufS + 16384;
#pragma unroll
    for (int rnd = 0; rnd < 2; ++rnd) {
      gload_lds16(gS + (size_t)rnd * 64 * Tn + ke, bufS + rnd * 8192 + w * 1024);
      gload_lds16(gV + (size_t)rnd * 64 * Tn + ke, bufV + rnd * 8192 + w * 1024);
    }
  };

  stage(0, 0);
  asm volatile("s_waitcnt vmcnt(0)" ::: "memory");
  __builtin_amdgcn_s_barrier();

  int cur = 0;
  for (int jt = 0; jt < nsteps; ++jt) {
    if (jt + 1 < nsteps) stage((jt + 1) * 64, cur ^ 1);
    const char* bS = lds + cur * 32768;
    const char* bV = bS + 16384;
#pragma unroll
    for (int ks = 0; ks < 2; ++ks) {
      short8 av[2], bs[4];
#pragma unroll
      for (int ma = 0; ma < 2; ++ma) {
        int row = dq * 32 + ma * 16 + l15;       // local d row (128)
        int c = (ks * 4 + lg) ^ (row & 7);
        av[ma] = *(const short8*)(bV + row * 128 + c * 16);
      }
#pragma unroll
      for (int ni = 0; ni < 4; ++ni) {
        int row = ih * 64 + ni * 16 + l15;       // local i row (128)
        int c = (ks * 4 + lg) ^ (row & 7);
        bs[ni] = *(const short8*)(bS + row * 128 + c * 16);
      }
#pragma unroll
      for (int ma = 0; ma < 2; ++ma)
#pragma unroll
        for (int ni = 0; ni < 4; ++ni)
          acc[ma][ni] = __builtin_amdgcn_mfma_f32_16x16x32_bf16(av[ma], bs[ni], acc[ma][ni], 0, 0, 0);
    }
    asm volatile("s_waitcnt vmcnt(0)" ::: "memory");
    __builtin_amdgcn_s_barrier();
    cur ^= 1;
  }

  // store: col(l15) = i, rows(lg*4+rr) = d -> 16B fp32 stores
  float* Oh = O + (size_t)g * Tn * Dn;
#pragma unroll
  for (int ma = 0; ma < 2; ++ma)
#pragma unroll
    for (int ni = 0; ni < 4; ++ni) {
      int iloc = ih * 64 + ni * 16 + l15;
      int d0 = dh * 128 + dq * 32 + ma * 16 + lg * 4;
      *(f32x4*)(Oh + (size_t)(ti * 128 + iloc) * Dn + d0) = acc[ma][ni];
    }
}

extern "C" void kernel_launch(void* const* d_in, const int* in_sizes, int n_in,
                              void* d_out, int out_size, void* d_ws, size_t ws_size,
                              hipStream_t stream) {
  const float* Q = (const float*)d_in[0];
  const float* V = (const float*)d_in[1];
  float* O = (float*)d_out;

  // ws: QR bf16 [8][T][N] (64 MiB) | VT bf16 [2][D][T] (2 MiB) | S bf16 [8][T][T] (64 MiB)
  uint16_t* QRw = (uint16_t*)d_ws;
  uint16_t* VTw = QRw + (size_t)NHEAD * Tn * Nn;
  uint16_t* Sw  = VTw + (size_t)2 * Dn * Tn;

  hipFuncSetAttribute((const void*)pv_kernel, hipFuncAttributeMaxDynamicSharedMemorySize, 65536);

  rope_kernel<<<((size_t)NHEAD * Tn * Nn / 4) / 256, 256, 0, stream>>>(Q, QRw);
  vt_kernel<<<(2 * Dn * Tn) / 256, 256, 0, stream>>>(V, VTw);
  qkt_kernel<<<1088, 256, 0, stream>>>(QRw, Sw);
  pv_kernel<<<256, 512, 65536, stream>>>(Sw, VTw, O);
}